// Round 1
// baseline (283.437 us; speedup 1.0000x reference)
//
#include <hip/hip_runtime.h>
#include <hip/hip_bf16.h>

#define IN_C  128
#define OUT_C 256
#define HIMG  56
#define WIMG  56
#define BIMG  32
#define KDIM  1152              // 9 * 128, GEMM K
#define HW    (HIMG * WIMG)     // 3136
#define NPIX  (BIMG * HW)       // 100352, GEMM N

#define BM 128
#define BN 128
#define BK 32
#define LDK 40                  // padded K pitch (bf16 elems); 80 B rows, 16B-aligned

typedef __attribute__((ext_vector_type(8))) short short8;
typedef __attribute__((ext_vector_type(4))) float float4_;

__device__ __forceinline__ unsigned short f32_to_bf16_rne(float f) {
    unsigned u = __builtin_bit_cast(unsigned, f);
    u += 0x7FFFu + ((u >> 16) & 1u);
    return (unsigned short)(u >> 16);
}

// One-shot repack: Wt[oc][r*128+ic] (bf16 bits) <- Wk[oc][ic*9+r] (fp32)
__global__ void repack_w(const float* __restrict__ Wk, unsigned short* __restrict__ Wt) {
    int idx = blockIdx.x * 256 + threadIdx.x;
    if (idx >= OUT_C * KDIM) return;
    int oc  = idx / KDIM;
    int rem = idx - oc * KDIM;
    int r   = rem >> 7;      // /128
    int ic  = rem & 127;
    Wt[idx] = f32_to_bf16_rne(Wk[oc * KDIM + ic * 9 + r]);
}

__global__ __launch_bounds__(256, 2) void conv_gemm(
    const float* __restrict__ x, const unsigned short* __restrict__ Wt,
    const float* __restrict__ bias, float* __restrict__ out)
{
    __shared__ short As[BM * LDK];   // [m][k] rows of 80 B
    __shared__ short Bs[BN * LDK];   // [n][k] rows of 80 B

    const int tid  = threadIdx.x;
    const int lane = tid & 63;
    const int wid  = tid >> 6;
    const int n0   = blockIdx.x * BN;
    const int oc0  = blockIdx.y * BM;

    // B-stage mapping: each thread owns pixel n = tid&127, k-halves kb2 = tid>>7
    const int bn   = tid & 127;
    const int kb2  = tid >> 7;          // 0..1 -> kb = kb2*2 + {0,1}
    const int n_g  = n0 + bn;
    const int bimg = n_g / HW;
    const int hw   = n_g - bimg * HW;
    const int hh   = hw / WIMG;
    const int ww   = hw - hh * WIMG;
    const float* xbase = x + (size_t)bimg * IN_C * HW + hh * WIMG + ww;

    // A-stage mapping: row m = tid>>1, k-offset (tid&1)*16
    const int am  = tid >> 1;
    const int ako = (tid & 1) * 16;

    const int wm = (wid >> 1) * 64;   // wave quadrant origin in m
    const int wn = (wid & 1) * 64;    // ... in n

    float4_ acc[4][4];
    #pragma unroll
    for (int i = 0; i < 4; ++i)
        #pragma unroll
        for (int j = 0; j < 4; ++j) acc[i][j] = (float4_)0.0f;

    const int mrow = wm + (lane & 15);
    const int kcol = (lane >> 4) * 8;

    for (int kt = 0; kt < KDIM / BK; ++kt) {   // 36 iters
        const int k0  = kt * BK;
        const int r   = kt >> 2;               // uniform kernel tap for this tile
        const int ic0 = (kt & 3) * 32;
        const int dh  = r / 3 - 1;
        const int dw  = r - (r / 3) * 3 - 1;

        // ---- stage A: bf16 copy from repacked weights ----
        {
            const unsigned short* src = Wt + (size_t)(oc0 + am) * KDIM + k0 + ako;
            short8 v0 = *(const short8*)(src);
            short8 v1 = *(const short8*)(src + 8);
            *(short8*)(&As[am * LDK + ako])     = v0;
            *(short8*)(&As[am * LDK + ako + 8]) = v1;
        }
        // ---- stage B: im2col gather, fp32 -> bf16, k-vectorized LDS write ----
        {
            const int h2 = hh + dh, w2 = ww + dw;
            const bool valid = ((unsigned)h2 < HIMG) && ((unsigned)w2 < WIMG);
            const float* src = xbase + dh * WIMG + dw;
            #pragma unroll
            for (int half = 0; half < 2; ++half) {
                const int kb = kb2 * 2 + half;
                short8 v;
                #pragma unroll
                for (int j = 0; j < 8; ++j) {
                    const int ic = ic0 + kb * 8 + j;
                    float f = valid ? src[(size_t)ic * HW] : 0.0f;
                    v[j] = (short)f32_to_bf16_rne(f);
                }
                *(short8*)(&Bs[bn * LDK + kb * 8]) = v;
            }
        }
        __syncthreads();

        // ---- 4x4 MFMA tile per wave ----
        short8 afr[4], bfr[4];
        #pragma unroll
        for (int i = 0; i < 4; ++i)
            afr[i] = *(const short8*)(&As[(mrow + i * 16) * LDK + kcol]);
        #pragma unroll
        for (int i = 0; i < 4; ++i)
            bfr[i] = *(const short8*)(&Bs[(wn + (lane & 15) + i * 16) * LDK + kcol]);
        #pragma unroll
        for (int mi = 0; mi < 4; ++mi)
            #pragma unroll
            for (int ni = 0; ni < 4; ++ni)
                acc[mi][ni] = __builtin_amdgcn_mfma_f32_16x16x32_bf16(
                    afr[mi], bfr[ni], acc[mi][ni], 0, 0, 0);
        __syncthreads();
    }

    // ---- epilogue: C/D layout col=lane&15, row=(lane>>4)*4+v (m89-verified) ----
    const int col  = lane & 15;
    const int rowg = (lane >> 4) * 4;
    #pragma unroll
    for (int mi = 0; mi < 4; ++mi) {
        #pragma unroll
        for (int v = 0; v < 4; ++v) {
            const int oc = oc0 + wm + mi * 16 + rowg + v;
            const float bv = bias[oc];
            #pragma unroll
            for (int ni = 0; ni < 4; ++ni) {
                const int n   = n0 + wn + ni * 16 + col;
                const int b_  = n / HW;
                const int hw_ = n - b_ * HW;
                out[(size_t)(b_ * OUT_C + oc) * HW + hw_] = acc[mi][ni][v] + bv;
            }
        }
    }
}

extern "C" void kernel_launch(void* const* d_in, const int* in_sizes, int n_in,
                              void* d_out, int out_size, void* d_ws, size_t ws_size,
                              hipStream_t stream) {
    const float* x    = (const float*)d_in[0];
    const float* Wk   = (const float*)d_in[1];
    const float* bias = (const float*)d_in[2];
    float* out        = (float*)d_out;
    unsigned short* Wt = (unsigned short*)d_ws;   // 256*1152*2 = 589,824 B

    repack_w<<<dim3((OUT_C * KDIM + 255) / 256), dim3(256), 0, stream>>>(Wk, Wt);
    conv_gemm<<<dim3(NPIX / BN, OUT_C / BM), dim3(256), 0, stream>>>(x, Wt, bias, out);
}

// Round 2
// 214.625 us; speedup vs baseline: 1.3206x; 1.3206x over previous
//
#include <hip/hip_runtime.h>
#include <hip/hip_bf16.h>

#define IN_C  128
#define OUT_C 256
#define HIMG  56
#define WIMG  56
#define BIMG  32
#define HW    (HIMG * WIMG)     // 3136
#define KW    1152              // 9 * 128, GEMM K

#define BM    128               // oc per block
#define TH    4                 // output rows per block
#define NLOC  224               // TH * 56 pixels per block
#define XROWS 6                 // TH + 2 halo
#define XCOLS 58                // 56 + 2 halo
#define NPIXT (XROWS * XCOLS)   // 348 staged pixels
#define LDK   40                // A-tile pitch (bf16), 80 B rows

typedef __attribute__((ext_vector_type(8))) short short8;
typedef __attribute__((ext_vector_type(4))) float float4_;

__device__ __forceinline__ unsigned short f32_to_bf16_rne(float f) {
    unsigned u = __builtin_bit_cast(unsigned, f);
    u += 0x7FFFu + ((u >> 16) & 1u);
    return (unsigned short)(u >> 16);
}

// One-shot repack: Wt[oc][r*128+ic] (bf16 bits) <- Wk[oc][ic*9+r] (fp32)
__global__ void repack_w(const float* __restrict__ Wk, unsigned short* __restrict__ Wt) {
    int idx = blockIdx.x * 256 + threadIdx.x;
    if (idx >= OUT_C * KW) return;
    int oc  = idx / KW;
    int rem = idx - oc * KW;
    int r   = rem >> 7;
    int ic  = rem & 127;
    Wt[idx] = f32_to_bf16_rne(Wk[oc * KW + ic * 9 + r]);
}

// Implicit-GEMM conv: M=oc(128/block), N=224 spatial pixels (4 rows x 56),
// K ordered as (icq outer, tap r inner). x slice staged ONCE per icq into LDS
// with halo; all 9 taps read shifted windows of it (kills 9x HBM refetch +
// 9x fp32->bf16 convert). Xs 16B-slot swizzle keeps b128 reads <=2-way.
__global__ __launch_bounds__(256, 2) void conv_gemm(
    const float* __restrict__ x, const unsigned short* __restrict__ Wt,
    const float* __restrict__ bias, float* __restrict__ out)
{
    __shared__ short As[BM * LDK];        // 10240 B, weights tile (one tap)
    __shared__ short Xs[NPIXT * 32];      // 22272 B, x slice [pix][32ic] w/ swizzle

    const int tid  = threadIdx.x;
    const int lane = tid & 63;
    const int wid  = tid >> 6;
    const int bx   = blockIdx.x;          // 0..447
    const int b    = bx / 14;
    const int h0   = (bx - b * 14) * TH;
    const int oc0  = blockIdx.y * BM;

    // 4 waves, each owns a 64(m) x 112(n) quadrant: 4x7 MFMA tiles
    const int wm = (wid >> 1) * 64;
    const int wn = (wid & 1) * 112;

    // per-lane geometry for the 7 n-fragments (loop-invariant)
    int lp0[7], outoff[7];
    #pragma unroll
    for (int ni = 0; ni < 7; ++ni) {
        int nl  = wn + ni * 16 + (lane & 15);
        int ht_ = nl / 56;
        int wt_ = nl - ht_ * 56;
        lp0[ni]    = (ht_ + 1) * XCOLS + (wt_ + 1);  // tap (0,0) pixel in Xs
        outoff[ni] = (h0 + ht_) * WIMG + wt_;
    }

    const short* aptr[4];
    #pragma unroll
    for (int mi = 0; mi < 4; ++mi)
        aptr[mi] = &As[(wm + mi * 16 + (lane & 15)) * LDK + (lane >> 4) * 8];

    float4_ acc[4][7];
    #pragma unroll
    for (int mi = 0; mi < 4; ++mi)
        #pragma unroll
        for (int ni = 0; ni < 7; ++ni) acc[mi][ni] = (float4_)0.0f;

    const int am = tid >> 1, ako = (tid & 1) * 16;
    const int q  = lane >> 4;

    // prefetch W regs for t=0
    short8 w0, w1;
    {
        const unsigned short* srcA = Wt + (size_t)(oc0 + am) * KW + 0 * 128 + 0 * 32 + ako;
        w0 = *(const short8*)srcA;
        w1 = *(const short8*)(srcA + 8);
    }

    for (int t = 0; t < 36; ++t) {        // t = icq*9 + r
        const int icq = t / 9;
        const int r   = t - icq * 9;

        if (r == 0) {
            // ---- stage Xs: x[b][icq*32..+32][h0-1..h0+4][-1..57] -> bf16 LDS ----
            for (int pix = tid; pix < NPIXT; pix += 256) {
                int row  = pix / XCOLS;
                int colw = pix - row * XCOLS;
                int h = h0 + row - 1;
                int w = colw - 1;
                bool valid = ((unsigned)h < HIMG) & ((unsigned)w < WIMG);
                const int sw = (pix >> 1) & 3;
                #pragma unroll
                for (int qb = 0; qb < 4; ++qb) {
                    const float* src = x + (size_t)(b * IN_C + icq * 32 + qb * 8) * HW
                                         + (ptrdiff_t)(h * WIMG + w);
                    short8 v;
                    #pragma unroll
                    for (int j = 0; j < 8; ++j) {
                        float f = valid ? src[(size_t)j * HW] : 0.0f;
                        v[j] = (short)f32_to_bf16_rne(f);
                    }
                    *(short8*)&Xs[pix * 32 + (qb ^ sw) * 8] = v;
                }
            }
        }

        // ---- write A tile from prefetched regs, prefetch next ----
        *(short8*)&As[am * LDK + ako]     = w0;
        *(short8*)&As[am * LDK + ako + 8] = w1;
        if (t < 35) {
            const int t1   = t + 1;
            const int icq1 = t1 / 9;
            const int r1   = t1 - icq1 * 9;
            const unsigned short* srcA =
                Wt + (size_t)(oc0 + am) * KW + r1 * 128 + icq1 * 32 + ako;
            w0 = *(const short8*)srcA;
            w1 = *(const short8*)(srcA + 8);
        }
        __syncthreads();

        // ---- MFMA: 4x7 tiles per wave, tap shift via doff ----
        const int doff = (r / 3 - 1) * XCOLS + (r - (r / 3) * 3 - 1);
        short8 afr[4], bfr[7];
        #pragma unroll
        for (int mi = 0; mi < 4; ++mi) afr[mi] = *(const short8*)aptr[mi];
        #pragma unroll
        for (int ni = 0; ni < 7; ++ni) {
            int lp   = lp0[ni] + doff;
            int slot = q ^ ((lp >> 1) & 3);
            bfr[ni]  = *(const short8*)&Xs[lp * 32 + slot * 8];
        }
        #pragma unroll
        for (int mi = 0; mi < 4; ++mi)
            #pragma unroll
            for (int ni = 0; ni < 7; ++ni)
                acc[mi][ni] = __builtin_amdgcn_mfma_f32_16x16x32_bf16(
                    afr[mi], bfr[ni], acc[mi][ni], 0, 0, 0);
        __syncthreads();
    }

    // ---- epilogue: C/D layout col=lane&15, row=(lane>>4)*4+v (m89-verified) ----
    const int rowg = (lane >> 4) * 4;
    #pragma unroll
    for (int mi = 0; mi < 4; ++mi) {
        #pragma unroll
        for (int v = 0; v < 4; ++v) {
            const int oc = oc0 + wm + mi * 16 + rowg + v;
            const float bv = bias[oc];
            float* obase = out + (size_t)(b * OUT_C + oc) * HW;
            #pragma unroll
            for (int ni = 0; ni < 7; ++ni)
                obase[outoff[ni]] = acc[mi][ni][v] + bv;
        }
    }
}

extern "C" void kernel_launch(void* const* d_in, const int* in_sizes, int n_in,
                              void* d_out, int out_size, void* d_ws, size_t ws_size,
                              hipStream_t stream) {
    const float* x    = (const float*)d_in[0];
    const float* Wk   = (const float*)d_in[1];
    const float* bias = (const float*)d_in[2];
    float* out        = (float*)d_out;
    unsigned short* Wt = (unsigned short*)d_ws;   // 256*1152*2 = 589,824 B

    repack_w<<<dim3((OUT_C * KW + 255) / 256), dim3(256), 0, stream>>>(Wk, Wt);
    conv_gemm<<<dim3(BIMG * (HIMG / TH), OUT_C / BM), dim3(256), 0, stream>>>(x, Wt, bias, out);
}